// Round 1
// baseline (4558.413 us; speedup 1.0000x reference)
//
#include <hip/hip_runtime.h>
#include <stdint.h>

typedef unsigned int u32;
typedef unsigned short u16;

#define DI __device__ __forceinline__

DI float bf2f(u16 h){ return __uint_as_float(((u32)h)<<16); }
DI u16 f2bf(float f){ u32 u = __float_as_uint(f); return (u16)((u + 0x7FFFu + ((u>>16)&1u))>>16); }

// ---------------- input table (element counts / offsets in fp32 staging buf) ----------------
#define NIN 29
__device__ const int g_in_off[NIN] = {
  0,27648,158720,289792,291520,291584,439040,439296,586752,587008,734464,
  734720,738816,738880,742976,743040,779904,779968,816832,816896,883456,
  883712,949248,949504,1015040,1015296,1080832,1081088,1081856};
#define CVT_TOTAL 1081859

// cvt-buffer float offsets
#define O_INP      0
#define O_COORD    27648
#define O_CELL     158720
#define O_ENCW     289792
#define O_ENCB     291520
#define O_UP1W     291584
#define O_UP1B     439040
#define O_UP2W     439296
#define O_UP2B     586752
#define O_UP3W     587008
#define O_UP3B     734464
#define O_SK1W     734720
#define O_SK1B     738816
#define O_SK2W     738880
#define O_SK2B     742976
#define O_DN4W     743040
#define O_DN4B     779904
#define O_DN5W     779968
#define O_DN5B     816832
#define O_MLPW0    816896
#define O_MLPB0    883456
#define O_MLPW1    883712
#define O_MLPB1    949248
#define O_MLPW2    949504
#define O_MLPB2    1015040
#define O_MLPW3    1015296
#define O_MLPB3    1080832
#define O_MLPW4    1081088
#define O_MLPB4    1081856

// workspace float offsets
#define W_CVT    16
#define W_UP1R   1082000
#define W_UP2R   1229456
#define W_UP3R   1376912
#define W_D4R    1524368
#define W_D5R    1561232
#define W_S1R    1598096
#define W_S2R    1602192
#define W_FEAT   1606288
#define W_FEAT1  2196112
#define W_FEAT2  4555408
#define W_FEAT3  13992592
#define W_FEAT4  51741328
#define W_FEAT5  61178512
// end: 63537808 floats = 254.2 MB

// ---------------- dtype detect: cell is constant 2/384 ----------------
__global__ void k_detect(const void* cell, int* flag){
  if (threadIdx.x == 0 && blockIdx.x == 0){
    u32 u = *(const u32*)cell;
    // bf16-packed constant => high half == low half; fp32 0x3BAAAAAB => not equal
    *flag = ((u >> 16) == (u & 0xFFFFu)) ? 1 : 0;
  }
}

struct Ptrs { const void* p[NIN]; };

__global__ __launch_bounds__(256) void k_convert(Ptrs ptrs, const int* __restrict__ flag, float* __restrict__ dst){
  int idx = blockIdx.x*256 + threadIdx.x;
  if (idx >= CVT_TOTAL) return;
  int bf = *flag;
  int i = 0;
  #pragma unroll
  for (int s = 1; s < NIN; ++s) if (idx >= g_in_off[s]) i = s;
  int local = idx - g_in_off[i];
  float v;
  if (bf) v = bf2f(((const u16*)ptrs.p[i])[local]);
  else    v = ((const float*)ptrs.p[i])[local];
  dst[idx] = v;
}

// ---------------- weight repack: OIHW -> [(ci*9+k)*Co + co] (and 1x1 -> [ci*Co+co]) ----------------
__global__ __launch_bounds__(256) void k_repack(const float* __restrict__ cvt, float* __restrict__ ws){
  int idx = blockIdx.x*256 + threadIdx.x;  // grid covers 524288 exactly
  const int srcoff[7] = {O_UP1W, O_UP2W, O_UP3W, O_DN4W, O_DN5W, O_SK1W, O_SK2W};
  const int dstoff[7] = {W_UP1R, W_UP2R, W_UP3R, W_D4R, W_D5R, W_S1R, W_S2R};
  int seg, base;
  if (idx < 442368)      { seg = idx / 147456;               base = idx - seg*147456; }
  else if (idx < 516096) { seg = 3 + (idx-442368)/36864;     base = (idx-442368) % 36864; }
  else                   { seg = 5 + (idx-516096)/4096;      base = (idx-516096) % 4096; }
  float v;
  if (seg < 3)      { int co = base & 255, rest = base >> 8; v = cvt[srcoff[seg] + co*576 + rest]; }
  else if (seg < 5) { int co = base & 63,  rest = base >> 6; v = cvt[srcoff[seg] + co*576 + rest]; }
  else              { int co = base & 63,  rest = base >> 6; v = cvt[srcoff[seg] + co*64  + rest]; }
  ws[dstoff[seg] + base] = v;
}

// ---------------- enc conv: 3->64, 3x3 pad1, NCHW in (tiny), NHWC out ----------------
__global__ __launch_bounds__(256) void k_enc(const float* __restrict__ cvt, float* __restrict__ feat){
  int gid = blockIdx.x*256 + threadIdx.x;
  int co = gid & 63, pix = gid >> 6;
  int x = pix % 48; int t = pix / 48; int y = t % 48; int b = t / 48;
  const float* w = cvt + O_ENCW + co*27;
  float acc = cvt[O_ENCB + co];
  const float* ip = cvt + O_INP + b*3*2304;
  #pragma unroll
  for (int ci = 0; ci < 3; ++ci)
    for (int dy = 0; dy < 3; ++dy){
      int iy = y + dy - 1;
      for (int dx = 0; dx < 3; ++dx){
        int ix = x + dx - 1;
        float v = (iy>=0 && iy<48 && ix>=0 && ix<48) ? ip[ci*2304 + iy*48 + ix] : 0.f;
        acc = fmaf(w[ci*9 + dy*3 + dx], v, acc);
      }
    }
  feat[pix*64 + co] = acc;
}

// ---------------- upconv 64->256 3x3 pad1 + fused pixel-shuffle, NHWC ----------------
template<int H>
__global__ __launch_bounds__(256) void k_upconv(const float* __restrict__ in, const float* __restrict__ wr,
                                                const float* __restrict__ bias, float* __restrict__ out){
  __shared__ float xs[64*101];           // [ci][pos], pos<100, stride 101 (bank-friendly)
  const int TW = H/8;
  int b = blockIdx.y;
  int y0 = (blockIdx.x / TW)*8, x0 = (blockIdx.x % TW)*8;
  int tid = threadIdx.x;
  {
    int c = tid & 63;
    for (int pos = tid>>6; pos < 100; pos += 4){
      int pr = pos/10, pc = pos - pr*10;
      int gy = y0 + pr - 1, gx = x0 + pc - 1;
      float v = 0.f;
      if (gy>=0 && gy<H && gx>=0 && gx<H) v = in[((b*H+gy)*H+gx)*64 + c];
      xs[c*101 + pos] = v;
    }
  }
  __syncthreads();
  int px = tid & 63; int py = px>>3, pxx = px&7;
  int cog = __builtin_amdgcn_readfirstlane(tid >> 6);   // wave-uniform co-group -> SGPR weights
  float acc[64];
  #pragma unroll
  for (int j=0;j<64;++j) acc[j] = bias[cog*64 + j];
  for (int ci = 0; ci < 64; ++ci){
    float xv[9];
    #pragma unroll
    for (int dy=0;dy<3;++dy)
      #pragma unroll
      for (int dx=0;dx<3;++dx)
        xv[dy*3+dx] = xs[ci*101 + (py+dy)*10 + (pxx+dx)];
    const float* w0 = wr + ci*(9*256) + cog*64;
    #pragma unroll
    for (int k=0;k<9;++k){
      const float* wk = w0 + k*256;
      float xk = xv[k];
      #pragma unroll
      for (int j=0;j<64;++j) acc[j] = fmaf(wk[j], xk, acc[j]);
    }
  }
  // pixel-shuffle store: conv channel co=c2*4+r*2+s -> out[2y+r][2x+s][c2]
  int oy = 2*(y0+py), ox = 2*(x0+pxx);
  const int W2 = 2*H;
  #pragma unroll
  for (int rs = 0; rs < 4; ++rs){
    int r = rs>>1, s = rs&1;
    float* op = out + ((b*W2 + oy + r)*W2 + ox + s)*64 + cog*16;
    #pragma unroll
    for (int u = 0; u < 4; ++u){
      float4 v = make_float4(acc[16*u+rs], acc[16*u+4+rs], acc[16*u+8+rs], acc[16*u+12+rs]);
      *(float4*)(op + u*4) = v;
    }
  }
}

// ---------------- stride-2 downconv 64->64 3x3 pad1, NHWC ----------------
template<int HO>
__global__ __launch_bounds__(256) void k_downconv(const float* __restrict__ in, const float* __restrict__ wr,
                                                  const float* __restrict__ bias, float* __restrict__ out){
  __shared__ float xs[32*323];          // [ci_local][row*19+col], 17x17 patch, padded strides
  const int HI = 2*HO;
  const int TW = HO/8;
  int b = blockIdx.y;
  int y0 = (blockIdx.x / TW)*8, x0 = (blockIdx.x % TW)*8;
  int tid = threadIdx.x;
  int px = tid & 63; int py = px>>3, pxx = px&7;
  int cog = __builtin_amdgcn_readfirstlane(tid >> 6);
  float acc[16];
  #pragma unroll
  for (int j=0;j<16;++j) acc[j] = bias[cog*16 + j];
  for (int half = 0; half < 2; ++half){
    if (half) __syncthreads();
    {
      int c = tid & 31;
      for (int pos = tid>>5; pos < 289; pos += 8){
        int row = pos/17, col = pos - row*17;
        int gy = 2*y0 - 1 + row, gx = 2*x0 - 1 + col;
        float v = 0.f;
        if (gy>=0 && gy<HI && gx>=0 && gx<HI) v = in[((b*HI+gy)*HI+gx)*64 + half*32 + c];
        xs[c*323 + row*19 + col] = v;
      }
    }
    __syncthreads();
    for (int cl = 0; cl < 32; ++cl){
      int ci = half*32 + cl;
      float xv[9];
      #pragma unroll
      for (int dy=0;dy<3;++dy)
        #pragma unroll
        for (int dx=0;dx<3;++dx)
          xv[dy*3+dx] = xs[cl*323 + (2*py+dy)*19 + (2*pxx+dx)];
      const float* w0 = wr + ci*(9*64) + cog*16;
      #pragma unroll
      for (int k=0;k<9;++k){
        const float* wk = w0 + k*64;
        float xk = xv[k];
        #pragma unroll
        for (int j=0;j<16;++j) acc[j] = fmaf(wk[j], xk, acc[j]);
      }
    }
  }
  float* op = out + ((b*HO + y0+py)*HO + x0+pxx)*64 + cog*16;
  #pragma unroll
  for (int u=0;u<4;++u) *(float4*)(op + u*4) = make_float4(acc[4*u],acc[4*u+1],acc[4*u+2],acc[4*u+3]);
}

// ---------------- 1x1 skip conv, accumulates (+=) into out, NHWC ----------------
template<int H>
__global__ __launch_bounds__(256) void k_skip(const float* __restrict__ in, const float* __restrict__ wr,
                                              const float* __restrict__ bias, float* __restrict__ out){
  __shared__ float xs[64*65];
  int b = blockIdx.y;
  int p0 = blockIdx.x * 64;
  int tid = threadIdx.x;
  {
    int c = tid & 63;
    #pragma unroll
    for (int p = tid>>6; p < 64; p += 4)
      xs[c*65 + p] = in[(b*H*H + p0 + p)*64 + c];
  }
  __syncthreads();
  int px = tid & 63;
  int cog = __builtin_amdgcn_readfirstlane(tid >> 6);
  float acc[16];
  #pragma unroll
  for (int j=0;j<16;++j) acc[j] = bias[cog*16 + j];
  for (int ci = 0; ci < 64; ++ci){
    float xv = xs[ci*65 + px];
    const float* wk = wr + ci*64 + cog*16;
    #pragma unroll
    for (int j=0;j<16;++j) acc[j] = fmaf(wk[j], xv, acc[j]);
  }
  float* op = out + (b*H*H + p0 + px)*64 + cog*16;
  #pragma unroll
  for (int u=0;u<4;++u){
    float4 v = *(float4*)(op + u*4);
    v.x += acc[4*u]; v.y += acc[4*u+1]; v.z += acc[4*u+2]; v.w += acc[4*u+3];
    *(float4*)(op + u*4) = v;
  }
}

// ---------------- query stage helpers (fp32 op sequence matched to numpy) ----------------
DI void shifted_coord(float cy, float cx, int e, float& cy_, float& cx_){
  float vx = (e & 2) ? 1.f : -1.f;
  float vy = (e & 1) ? 1.f : -1.f;
  float sy = (float)((double)vx*(1.0/48.0) + 1e-6);
  float sx = (float)((double)vy*(1.0/48.0) + 1e-6);
  const float clo = (float)(-1.0 + 1e-6), chi = (float)(1.0 - 1e-6);
  cy_ = fminf(fmaxf(__fadd_rn(cy, sy), clo), chi);
  cx_ = fminf(fmaxf(__fadd_rn(cx, sx), clo), chi);
}
DI int nidx(float c_, int hL){
  float f = __fadd_rn(__fmul_rn(__fadd_rn(c_, 1.f), (float)hL*0.5f), -0.5f);
  int i = (int)rintf(f);
  return max(0, min(hL-1, i));
}

DI void mlp_hidden(const u16* IN, u16* OUT, const float* __restrict__ W, const float* __restrict__ Bs,
                   int c0, int lane){
  float acc[64];
  #pragma unroll
  for (int j=0;j<64;++j) acc[j] = Bs[c0+j];
  for (int k=0;k<256;++k){
    float xv = bf2f(IN[k*64 + lane]);
    const float* wk = W + k*256 + c0;
    #pragma unroll
    for (int j=0;j<64;++j) acc[j] = fmaf(wk[j], xv, acc[j]);
  }
  #pragma unroll
  for (int j=0;j<64;++j) OUT[(c0+j)*64 + lane] = f2bf(fmaxf(acc[j], 0.f));
}

// ---------------- fused gather + MLP + ensemble + bilinear ----------------
__global__ __launch_bounds__(256) void k_query(const float* __restrict__ cvt,
    const float* __restrict__ feat, const float* __restrict__ feat3,
    const float* __restrict__ feat4, const float* __restrict__ feat5,
    const int* __restrict__ flagp, void* __restrict__ outv){
  __shared__ char smem[65536];
  u16* Abuf = (u16*)smem;                // [256][64] bf16 activations
  u16* Bbuf = (u16*)(smem + 32768);      // [256][64]
  float* pred = (float*)(smem + 32768);  // reuses Bbuf (dead during layer 4)
  int tid = threadIdx.x;

  // ---- gather: 64 rows (16 queries x 4 ensembles), 4 parts/row = 4 pyramid levels ----
  {
    int r = tid >> 2, part = tid & 3;
    int gq = blockIdx.x*16 + (r>>2);
    int e = r & 3;
    int b = gq >> 14, q = gq & 16383;
    float cy = cvt[O_COORD + (b*16384+q)*2 + 0];
    float cx = cvt[O_COORD + (b*16384+q)*2 + 1];
    float cy_, cx_; shifted_coord(cy, cx, e, cy_, cx_);
    int hL = (part==0) ? 48 : (part==1) ? 96 : (part==2) ? 192 : 384;
    const float* fp = (part==0) ? feat : (part==1) ? feat5 : (part==2) ? feat4 : feat3;
    int iy = nidx(cy_, hL), ix = nidx(cx_, hL);
    const float4* src = (const float4*)(fp + ((b*hL + iy)*hL + ix)*64);
    #pragma unroll
    for (int i=0;i<16;++i){
      float4 v = src[i];
      int k = part*64 + i*4;
      Abuf[(k+0)*64 + r] = f2bf(v.x);
      Abuf[(k+1)*64 + r] = f2bf(v.y);
      Abuf[(k+2)*64 + r] = f2bf(v.z);
      Abuf[(k+3)*64 + r] = f2bf(v.w);
    }
  }
  __syncthreads();

  // ---- MLP: lane = row, wave = 64-col block; weights via wave-uniform (scalar) loads ----
  int lane = tid & 63;
  int wv = __builtin_amdgcn_readfirstlane(tid >> 6);
  int c0 = wv * 64;

  float relv[4];
  {
    int gq = blockIdx.x*16 + (lane>>2);
    int e = lane & 3;
    int b = gq >> 14, q = gq & 16383;
    float cy = cvt[O_COORD + (b*16384+q)*2 + 0];
    float cx = cvt[O_COORD + (b*16384+q)*2 + 1];
    float cy_, cx_; shifted_coord(cy, cx, e, cy_, cx_);
    int iy = nidx(cy_, 48), ix = nidx(cx_, 48);
    float qy = -1.f + (2.f*iy + 1.f)*(1.f/48.f);
    float qx = -1.f + (2.f*ix + 1.f)*(1.f/48.f);
    relv[0] = (cy - qy)*48.f;
    relv[1] = (cx - qx)*48.f;
    relv[2] = cvt[O_CELL + (b*16384+q)*2 + 0]*48.f;
    relv[3] = cvt[O_CELL + (b*16384+q)*2 + 1]*48.f;
  }

  // layer 0 (K=256 bf16 features + 4 fp32 rel dims)
  {
    const float* W = cvt + O_MLPW0;
    const float* Bs = cvt + O_MLPB0;
    float acc[64];
    #pragma unroll
    for (int j=0;j<64;++j) acc[j] = Bs[c0+j];
    #pragma unroll
    for (int t=0;t<4;++t){
      const float* wk = W + (256+t)*256 + c0;
      float xv = relv[t];
      #pragma unroll
      for (int j=0;j<64;++j) acc[j] = fmaf(wk[j], xv, acc[j]);
    }
    for (int k=0;k<256;++k){
      float xv = bf2f(Abuf[k*64 + lane]);
      const float* wk = W + k*256 + c0;
      #pragma unroll
      for (int j=0;j<64;++j) acc[j] = fmaf(wk[j], xv, acc[j]);
    }
    #pragma unroll
    for (int j=0;j<64;++j) Bbuf[(c0+j)*64 + lane] = f2bf(fmaxf(acc[j], 0.f));
  }
  __syncthreads();
  mlp_hidden(Bbuf, Abuf, cvt + O_MLPW1, cvt + O_MLPB1, c0, lane);
  __syncthreads();
  mlp_hidden(Abuf, Bbuf, cvt + O_MLPW2, cvt + O_MLPB2, c0, lane);
  __syncthreads();
  mlp_hidden(Bbuf, Abuf, cvt + O_MLPW3, cvt + O_MLPB3, c0, lane);
  __syncthreads();

  // layer 4: 256 -> 3, wave 0 only; pred lands in Bbuf space (dead)
  if (wv == 0){
    const float* W4 = cvt + O_MLPW4;
    float a0 = cvt[O_MLPB4+0], a1 = cvt[O_MLPB4+1], a2 = cvt[O_MLPB4+2];
    for (int k=0;k<256;++k){
      float xv = bf2f(Abuf[k*64 + lane]);
      a0 = fmaf(W4[k*3+0], xv, a0);
      a1 = fmaf(W4[k*3+1], xv, a1);
      a2 = fmaf(W4[k*3+2], xv, a2);
    }
    pred[lane*3+0] = a0; pred[lane*3+1] = a1; pred[lane*3+2] = a2;
  }
  __syncthreads();

  // ---- ensemble combine + bilinear(inp) + store ----
  if (tid < 16){
    int gq = blockIdx.x*16 + tid;
    int b = gq >> 14, q = gq & 16383;
    float cy = cvt[O_COORD + (b*16384+q)*2 + 0];
    float cx = cvt[O_COORD + (b*16384+q)*2 + 1];
    float a[4];
    #pragma unroll
    for (int e=0;e<4;++e){
      float cy_, cx_; shifted_coord(cy, cx, e, cy_, cx_);
      int iy = nidx(cy_, 48), ix = nidx(cx_, 48);
      float qy = -1.f + (2.f*iy + 1.f)*(1.f/48.f);
      float qx = -1.f + (2.f*ix + 1.f)*(1.f/48.f);
      float ry = (cy - qy)*48.f, rx = (cx - qx)*48.f;
      a[e] = fabsf(ry*rx) + 1e-9f;
    }
    float tot = a[0]+a[1]+a[2]+a[3];
    // bilinear border sample of inp (NCHW fp32 staging)
    float fy = fminf(fmaxf((cy+1.f)*24.f - 0.5f, 0.f), 47.f);
    float fx = fminf(fmaxf((cx+1.f)*24.f - 0.5f, 0.f), 47.f);
    float y0f = floorf(fy), x0f = floorf(fx);
    float wy = fy - y0f, wx = fx - x0f;
    int y0 = (int)y0f, x0 = (int)x0f;
    int y1 = min(y0+1, 47), x1 = min(x0+1, 47);
    int bf = *flagp;
    #pragma unroll
    for (int ch=0; ch<3; ++ch){
      const float* ip = cvt + O_INP + (b*3 + ch)*2304;
      float v00 = ip[y0*48+x0], v01 = ip[y0*48+x1], v10 = ip[y1*48+x0], v11 = ip[y1*48+x1];
      float v = v00*(1.f-wy)*(1.f-wx) + v01*(1.f-wy)*wx + v10*wy*(1.f-wx) + v11*wy*wx;
      #pragma unroll
      for (int e=0;e<4;++e)
        v += pred[(tid*4+e)*3 + ch] * (a[3-e]/tot);   // local-ensemble diagonal swap
      int oi = (b*16384+q)*3 + ch;
      if (bf) ((u16*)outv)[oi] = f2bf(v);
      else    ((float*)outv)[oi] = v;
    }
  }
}

extern "C" void kernel_launch(void* const* d_in, const int* in_sizes, int n_in,
                              void* d_out, int out_size, void* d_ws, size_t ws_size,
                              hipStream_t stream){
  float* ws = (float*)d_ws;
  int* flag = (int*)d_ws;
  float* cvt = ws + W_CVT;
  Ptrs ptrs;
  for (int i = 0; i < NIN && i < n_in; ++i) ptrs.p[i] = d_in[i];

  k_detect<<<1, 64, 0, stream>>>(d_in[2], flag);
  k_convert<<<(CVT_TOTAL+255)/256, 256, 0, stream>>>(ptrs, flag, cvt);
  k_repack<<<2048, 256, 0, stream>>>(cvt, ws);
  k_enc<<<2304, 256, 0, stream>>>(cvt, ws + W_FEAT);
  k_upconv<48> <<<dim3(36, 4), 256, 0, stream>>>(ws+W_FEAT,  ws+W_UP1R, cvt+O_UP1B, ws+W_FEAT1);
  k_upconv<96> <<<dim3(144,4), 256, 0, stream>>>(ws+W_FEAT1, ws+W_UP2R, cvt+O_UP2B, ws+W_FEAT2);
  k_upconv<192><<<dim3(576,4), 256, 0, stream>>>(ws+W_FEAT2, ws+W_UP3R, cvt+O_UP3B, ws+W_FEAT3);
  k_downconv<192><<<dim3(576,4), 256, 0, stream>>>(ws+W_FEAT3, ws+W_D4R, cvt+O_DN4B, ws+W_FEAT4);
  k_skip<192>    <<<dim3(576,4), 256, 0, stream>>>(ws+W_FEAT2, ws+W_S1R, cvt+O_SK1B, ws+W_FEAT4);
  k_downconv<96> <<<dim3(144,4), 256, 0, stream>>>(ws+W_FEAT4, ws+W_D5R, cvt+O_DN5B, ws+W_FEAT5);
  k_skip<96>     <<<dim3(144,4), 256, 0, stream>>>(ws+W_FEAT1, ws+W_S2R, cvt+O_SK2B, ws+W_FEAT5);
  k_query<<<4096, 256, 0, stream>>>(cvt, ws+W_FEAT, ws+W_FEAT3, ws+W_FEAT4, ws+W_FEAT5, flag, d_out);
}

// Round 2
// 2220.671 us; speedup vs baseline: 2.0527x; 2.0527x over previous
//
#include <hip/hip_runtime.h>
#include <stdint.h>

typedef unsigned int u32;
typedef unsigned short u16;

#define DI __device__ __forceinline__

DI float bf2f(u16 h){ return __uint_as_float(((u32)h)<<16); }
DI u16 f2bf(float f){ u32 u = __float_as_uint(f); return (u16)((u + 0x7FFFu + ((u>>16)&1u))>>16); }
DI u32 pack2(float a, float b){ return (u32)f2bf(a) | ((u32)f2bf(b)<<16); }

typedef __attribute__((ext_vector_type(8))) short bf16x8;
typedef __attribute__((ext_vector_type(4))) float f32x4;

// ---------------- input table (element counts / offsets in fp32 staging buf) ----------------
#define NIN 29
__device__ const int g_in_off[NIN] = {
  0,27648,158720,289792,291520,291584,439040,439296,586752,587008,734464,
  734720,738816,738880,742976,743040,779904,779968,816832,816896,883456,
  883712,949248,949504,1015040,1015296,1080832,1081088,1081856};
#define CVT_TOTAL 1081859

// cvt-buffer float offsets
#define O_INP      0
#define O_COORD    27648
#define O_CELL     158720
#define O_ENCW     289792
#define O_ENCB     291520
#define O_UP1W     291584
#define O_UP1B     439040
#define O_UP2W     439296
#define O_UP2B     586752
#define O_UP3W     587008
#define O_UP3B     734464
#define O_SK1W     734720
#define O_SK1B     738816
#define O_SK2W     738880
#define O_SK2B     742976
#define O_DN4W     743040
#define O_DN4B     779904
#define O_DN5W     779968
#define O_DN5B     816832
#define O_MLPW0    816896
#define O_MLPB0    883456
#define O_MLPW1    883712
#define O_MLPB1    949248
#define O_MLPW2    949504
#define O_MLPB2    1015040
#define O_MLPW3    1015296
#define O_MLPB3    1080832
#define O_MLPW4    1081088
#define O_MLPB4    1081856

// workspace float offsets
#define W_CVT    16
#define W_UP1R   1082000
#define W_UP2R   1229456
#define W_UP3R   1376912
#define W_D4R    1524368
#define W_D5R    1561232
#define W_S1R    1598096
#define W_S2R    1602192
#define W_FEAT   1606288
#define W_FEAT1  2196112
#define W_FEAT2  4555408
#define W_FEAT3  13992592
#define W_FEAT4  51741328
#define W_FEAT5  61178512
#define W_MFW    63537808   // MLP MFMA weight fragments (u16), 274432 elems = 137216 floats
// end: 63675024 floats = 254.7 MB

// MLP fragment layer offsets (u16 elements)
#define FO_L0 0
#define FO_L1 73728
#define FO_L2 139264
#define FO_L3 204800
#define FO_L4 270336
#define FRAG_TOTAL 274432

#define AST 296   // Abuf row stride in bf16 (592 B: 16B-aligned, bank step 20 -> <=2-way)

// ---------------- dtype detect: cell is constant 2/384 ----------------
__global__ void k_detect(const void* cell, int* flag){
  if (threadIdx.x == 0 && blockIdx.x == 0){
    u32 u = *(const u32*)cell;
    *flag = ((u >> 16) == (u & 0xFFFFu)) ? 1 : 0;
  }
}

struct Ptrs { const void* p[NIN]; };

__global__ __launch_bounds__(256) void k_convert(Ptrs ptrs, const int* __restrict__ flag, float* __restrict__ dst){
  int idx = blockIdx.x*256 + threadIdx.x;
  if (idx >= CVT_TOTAL) return;
  int bf = *flag;
  int i = 0;
  #pragma unroll
  for (int s = 1; s < NIN; ++s) if (idx >= g_in_off[s]) i = s;
  int local = idx - g_in_off[i];
  float v;
  if (bf) v = bf2f(((const u16*)ptrs.p[i])[local]);
  else    v = ((const float*)ptrs.p[i])[local];
  dst[idx] = v;
}

// ---------------- weight repack: OIHW -> [(ci*9+k)*Co + co] (and 1x1 -> [ci*Co+co]) ----------------
__global__ __launch_bounds__(256) void k_repack(const float* __restrict__ cvt, float* __restrict__ ws){
  int idx = blockIdx.x*256 + threadIdx.x;  // grid covers 524288 exactly
  const int srcoff[7] = {O_UP1W, O_UP2W, O_UP3W, O_DN4W, O_DN5W, O_SK1W, O_SK2W};
  const int dstoff[7] = {W_UP1R, W_UP2R, W_UP3R, W_D4R, W_D5R, W_S1R, W_S2R};
  int seg, base;
  if (idx < 442368)      { seg = idx / 147456;               base = idx - seg*147456; }
  else if (idx < 516096) { seg = 3 + (idx-442368)/36864;     base = (idx-442368) % 36864; }
  else                   { seg = 5 + (idx-516096)/4096;      base = (idx-516096) % 4096; }
  float v;
  if (seg < 3)      { int co = base & 255, rest = base >> 8; v = cvt[srcoff[seg] + co*576 + rest]; }
  else if (seg < 5) { int co = base & 63,  rest = base >> 6; v = cvt[srcoff[seg] + co*576 + rest]; }
  else              { int co = base & 63,  rest = base >> 6; v = cvt[srcoff[seg] + co*64  + rest]; }
  ws[dstoff[seg] + base] = v;
}

// ---------------- MLP weight repack into MFMA B-fragment order (bf16) ----------------
// chunk (layer l, kc, nt): dst[((chunk)*64 + lane)*8 + j] = bf16(W_l[k][n]),
//   k = kc*32 + (lane>>4)*8 + j, n = nt*16 + (lane&15); zero-padded outside.
__global__ __launch_bounds__(256) void k_repack_mlp(const float* __restrict__ cvt, u16* __restrict__ dst){
  int idx = blockIdx.x*256 + threadIdx.x;   // grid covers FRAG_TOTAL exactly
  int l, base;
  if (idx < FO_L1)      { l = 0; base = idx; }
  else if (idx < FO_L2) { l = 1; base = idx - FO_L1; }
  else if (idx < FO_L3) { l = 2; base = idx - FO_L2; }
  else if (idx < FO_L4) { l = 3; base = idx - FO_L3; }
  else                  { l = 4; base = idx - FO_L4; }
  int t = base & 511, c = base >> 9;
  int L = t >> 3, j = t & 7;
  int ntiles = (l == 4) ? 1 : 16;
  int kc = c / ntiles, nt = c % ntiles;
  int k = kc*32 + (L>>4)*8 + j;
  int n = nt*16 + (L&15);
  const int srcw[5] = {O_MLPW0, O_MLPW1, O_MLPW2, O_MLPW3, O_MLPW4};
  int Kvalid = (l == 0) ? 260 : 256;
  int N = (l == 4) ? 3 : 256;
  float v = 0.f;
  if (k < Kvalid && n < N) v = cvt[srcw[l] + k*N + n];
  dst[idx] = f2bf(v);
}

// ---------------- enc conv: 3->64, 3x3 pad1, NCHW in (tiny), NHWC out ----------------
__global__ __launch_bounds__(256) void k_enc(const float* __restrict__ cvt, float* __restrict__ feat){
  int gid = blockIdx.x*256 + threadIdx.x;
  int co = gid & 63, pix = gid >> 6;
  int x = pix % 48; int t = pix / 48; int y = t % 48; int b = t / 48;
  const float* w = cvt + O_ENCW + co*27;
  float acc = cvt[O_ENCB + co];
  const float* ip = cvt + O_INP + b*3*2304;
  #pragma unroll
  for (int ci = 0; ci < 3; ++ci)
    for (int dy = 0; dy < 3; ++dy){
      int iy = y + dy - 1;
      for (int dx = 0; dx < 3; ++dx){
        int ix = x + dx - 1;
        float v = (iy>=0 && iy<48 && ix>=0 && ix<48) ? ip[ci*2304 + iy*48 + ix] : 0.f;
        acc = fmaf(w[ci*9 + dy*3 + dx], v, acc);
      }
    }
  feat[pix*64 + co] = acc;
}

// ---------------- upconv 64->256 3x3 pad1 + fused pixel-shuffle, NHWC ----------------
template<int H>
__global__ __launch_bounds__(256) void k_upconv(const float* __restrict__ in, const float* __restrict__ wr,
                                                const float* __restrict__ bias, float* __restrict__ out){
  __shared__ float xs[64*101];
  const int TW = H/8;
  int b = blockIdx.y;
  int y0 = (blockIdx.x / TW)*8, x0 = (blockIdx.x % TW)*8;
  int tid = threadIdx.x;
  {
    int c = tid & 63;
    for (int pos = tid>>6; pos < 100; pos += 4){
      int pr = pos/10, pc = pos - pr*10;
      int gy = y0 + pr - 1, gx = x0 + pc - 1;
      float v = 0.f;
      if (gy>=0 && gy<H && gx>=0 && gx<H) v = in[((b*H+gy)*H+gx)*64 + c];
      xs[c*101 + pos] = v;
    }
  }
  __syncthreads();
  int px = tid & 63; int py = px>>3, pxx = px&7;
  int cog = __builtin_amdgcn_readfirstlane(tid >> 6);
  float acc[64];
  #pragma unroll
  for (int j=0;j<64;++j) acc[j] = bias[cog*64 + j];
  for (int ci = 0; ci < 64; ++ci){
    float xv[9];
    #pragma unroll
    for (int dy=0;dy<3;++dy)
      #pragma unroll
      for (int dx=0;dx<3;++dx)
        xv[dy*3+dx] = xs[ci*101 + (py+dy)*10 + (pxx+dx)];
    const float* w0 = wr + ci*(9*256) + cog*64;
    #pragma unroll
    for (int k=0;k<9;++k){
      const float* wk = w0 + k*256;
      float xk = xv[k];
      #pragma unroll
      for (int j=0;j<64;++j) acc[j] = fmaf(wk[j], xk, acc[j]);
    }
  }
  int oy = 2*(y0+py), ox = 2*(x0+pxx);
  const int W2 = 2*H;
  #pragma unroll
  for (int rs = 0; rs < 4; ++rs){
    int r = rs>>1, s = rs&1;
    float* op = out + ((b*W2 + oy + r)*W2 + ox + s)*64 + cog*16;
    #pragma unroll
    for (int u = 0; u < 4; ++u){
      float4 v = make_float4(acc[16*u+rs], acc[16*u+4+rs], acc[16*u+8+rs], acc[16*u+12+rs]);
      *(float4*)(op + u*4) = v;
    }
  }
}

// ---------------- stride-2 downconv 64->64 3x3 pad1, NHWC ----------------
template<int HO>
__global__ __launch_bounds__(256) void k_downconv(const float* __restrict__ in, const float* __restrict__ wr,
                                                  const float* __restrict__ bias, float* __restrict__ out){
  __shared__ float xs[32*323];
  const int HI = 2*HO;
  const int TW = HO/8;
  int b = blockIdx.y;
  int y0 = (blockIdx.x / TW)*8, x0 = (blockIdx.x % TW)*8;
  int tid = threadIdx.x;
  int px = tid & 63; int py = px>>3, pxx = px&7;
  int cog = __builtin_amdgcn_readfirstlane(tid >> 6);
  float acc[16];
  #pragma unroll
  for (int j=0;j<16;++j) acc[j] = bias[cog*16 + j];
  for (int half = 0; half < 2; ++half){
    if (half) __syncthreads();
    {
      int c = tid & 31;
      for (int pos = tid>>5; pos < 289; pos += 8){
        int row = pos/17, col = pos - row*17;
        int gy = 2*y0 - 1 + row, gx = 2*x0 - 1 + col;
        float v = 0.f;
        if (gy>=0 && gy<HI && gx>=0 && gx<HI) v = in[((b*HI+gy)*HI+gx)*64 + half*32 + c];
        xs[c*323 + row*19 + col] = v;
      }
    }
    __syncthreads();
    for (int cl = 0; cl < 32; ++cl){
      int ci = half*32 + cl;
      float xv[9];
      #pragma unroll
      for (int dy=0;dy<3;++dy)
        #pragma unroll
        for (int dx=0;dx<3;++dx)
          xv[dy*3+dx] = xs[cl*323 + (2*py+dy)*19 + (2*pxx+dx)];
      const float* w0 = wr + ci*(9*64) + cog*16;
      #pragma unroll
      for (int k=0;k<9;++k){
        const float* wk = w0 + k*64;
        float xk = xv[k];
        #pragma unroll
        for (int j=0;j<16;++j) acc[j] = fmaf(wk[j], xk, acc[j]);
      }
    }
  }
  float* op = out + ((b*HO + y0+py)*HO + x0+pxx)*64 + cog*16;
  #pragma unroll
  for (int u=0;u<4;++u) *(float4*)(op + u*4) = make_float4(acc[4*u],acc[4*u+1],acc[4*u+2],acc[4*u+3]);
}

// ---------------- 1x1 skip conv, accumulates (+=) into out, NHWC ----------------
template<int H>
__global__ __launch_bounds__(256) void k_skip(const float* __restrict__ in, const float* __restrict__ wr,
                                              const float* __restrict__ bias, float* __restrict__ out){
  __shared__ float xs[64*65];
  int b = blockIdx.y;
  int p0 = blockIdx.x * 64;
  int tid = threadIdx.x;
  {
    int c = tid & 63;
    #pragma unroll
    for (int p = tid>>6; p < 64; p += 4)
      xs[c*65 + p] = in[(b*H*H + p0 + p)*64 + c];
  }
  __syncthreads();
  int px = tid & 63;
  int cog = __builtin_amdgcn_readfirstlane(tid >> 6);
  float acc[16];
  #pragma unroll
  for (int j=0;j<16;++j) acc[j] = bias[cog*16 + j];
  for (int ci = 0; ci < 64; ++ci){
    float xv = xs[ci*65 + px];
    const float* wk = wr + ci*64 + cog*16;
    #pragma unroll
    for (int j=0;j<16;++j) acc[j] = fmaf(wk[j], xv, acc[j]);
  }
  float* op = out + (b*H*H + p0 + px)*64 + cog*16;
  #pragma unroll
  for (int u=0;u<4;++u){
    float4 v = *(float4*)(op + u*4);
    v.x += acc[4*u]; v.y += acc[4*u+1]; v.z += acc[4*u+2]; v.w += acc[4*u+3];
    *(float4*)(op + u*4) = v;
  }
}

// ---------------- query stage helpers (fp32 op sequence matched to numpy) ----------------
DI void shifted_coord(float cy, float cx, int e, float& cy_, float& cx_){
  float vx = (e & 2) ? 1.f : -1.f;
  float vy = (e & 1) ? 1.f : -1.f;
  float sy = (float)((double)vx*(1.0/48.0) + 1e-6);
  float sx = (float)((double)vy*(1.0/48.0) + 1e-6);
  const float clo = (float)(-1.0 + 1e-6), chi = (float)(1.0 - 1e-6);
  cy_ = fminf(fmaxf(__fadd_rn(cy, sy), clo), chi);
  cx_ = fminf(fmaxf(__fadd_rn(cx, sx), clo), chi);
}
DI int nidx(float c_, int hL){
  float f = __fadd_rn(__fmul_rn(__fadd_rn(c_, 1.f), (float)hL*0.5f), -0.5f);
  int i = (int)rintf(f);
  return max(0, min(hL-1, i));
}

// ---------------- MFMA MLP layer helpers ----------------
// A-frag: lane holds A[m=lane&15][k=(lane>>4)*8+j]; B-frag: B[k=(lane>>4)*8+j][n=lane&15]
// C/D: col=lane&15, row=(lane>>4)*4+reg
template<int KC>
DI void layer_compute(const u16* __restrict__ Ab, const u16* __restrict__ wf,
                      const float* __restrict__ bias, int lane, int wv, f32x4 (&acc)[4][4]){
  int col = lane & 15, quad = lane >> 4;
  #pragma unroll
  for (int mt=0;mt<4;++mt)
    #pragma unroll
    for (int nt=0;nt<4;++nt){
      float bv = bias[wv*64 + nt*16 + col];
      acc[mt][nt] = (f32x4){bv,bv,bv,bv};
    }
  for (int kc=0; kc<KC; ++kc){
    bf16x8 a[4], b[4];
    #pragma unroll
    for (int mt=0;mt<4;++mt)
      a[mt] = *(const bf16x8*)(Ab + (mt*16+col)*AST + kc*32 + quad*8);
    #pragma unroll
    for (int nt=0;nt<4;++nt)
      b[nt] = *(const bf16x8*)(wf + ((kc*16 + wv*4 + nt)*64 + lane)*8);
    #pragma unroll
    for (int mt=0;mt<4;++mt)
      #pragma unroll
      for (int nt=0;nt<4;++nt)
        acc[mt][nt] = __builtin_amdgcn_mfma_f32_16x16x32_bf16(a[mt], b[nt], acc[mt][nt], 0, 0, 0);
  }
}

DI void layer_store(u16* __restrict__ Ab, f32x4 (&acc)[4][4], int lane, int wv){
  int col = lane & 15, quad = lane >> 4;
  #pragma unroll
  for (int mt=0;mt<4;++mt)
    #pragma unroll
    for (int nt=0;nt<4;++nt)
      #pragma unroll
      for (int r=0;r<4;++r)
        Ab[(mt*16 + quad*4 + r)*AST + wv*64 + nt*16 + col] = f2bf(fmaxf(acc[mt][nt][r], 0.f));
}

// ---------------- fused gather + MFMA MLP + ensemble + bilinear ----------------
__global__ __launch_bounds__(256) void k_query(const float* __restrict__ cvt,
    const float* __restrict__ feat, const float* __restrict__ feat3,
    const float* __restrict__ feat4, const float* __restrict__ feat5,
    const u16* __restrict__ wfrag, const int* __restrict__ flagp, void* __restrict__ outv){
  __shared__ u16 Abuf[64*AST];      // 37888 B, [row m][k]
  __shared__ float predbuf[64*3];
  int tid = threadIdx.x;

  // ---- gather: 64 rows (16 queries x 4 ensembles), 4 parts/row = 4 pyramid levels ----
  {
    int r = tid >> 2, part = tid & 3;
    int gq = blockIdx.x*16 + (r>>2);
    int e = r & 3;
    int b = gq >> 14, q = gq & 16383;
    float cy = cvt[O_COORD + (b*16384+q)*2 + 0];
    float cx = cvt[O_COORD + (b*16384+q)*2 + 1];
    float cy_, cx_; shifted_coord(cy, cx, e, cy_, cx_);
    int hL = (part==0) ? 48 : (part==1) ? 96 : (part==2) ? 192 : 384;
    const float* fp = (part==0) ? feat : (part==1) ? feat5 : (part==2) ? feat4 : feat3;
    int iy = nidx(cy_, hL), ix = nidx(cx_, hL);
    const float4* src = (const float4*)(fp + ((b*hL + iy)*hL + ix)*64);
    u32* dst = (u32*)((char*)Abuf + r*(AST*2) + part*128);
    #pragma unroll
    for (int i=0;i<16;++i){
      float4 v = src[i];
      dst[i*2+0] = pack2(v.x, v.y);
      dst[i*2+1] = pack2(v.z, v.w);
    }
  }
  // ---- rel features into K=256..259, zeros to 287 (layer-0 K padded to 288) ----
  if (tid < 64){
    int gq = blockIdx.x*16 + (tid>>2);
    int e = tid & 3;
    int b = gq >> 14, q = gq & 16383;
    float cy = cvt[O_COORD + (b*16384+q)*2 + 0];
    float cx = cvt[O_COORD + (b*16384+q)*2 + 1];
    float cy_, cx_; shifted_coord(cy, cx, e, cy_, cx_);
    int iy = nidx(cy_, 48), ix = nidx(cx_, 48);
    float qy = -1.f + (2.f*iy + 1.f)*(1.f/48.f);
    float qx = -1.f + (2.f*ix + 1.f)*(1.f/48.f);
    float r0 = (cy - qy)*48.f;
    float r1 = (cx - qx)*48.f;
    float r2 = cvt[O_CELL + (b*16384+q)*2 + 0]*48.f;
    float r3 = cvt[O_CELL + (b*16384+q)*2 + 1]*48.f;
    u32* dst = (u32*)((char*)Abuf + tid*(AST*2) + 512);
    dst[0] = pack2(r0, r1);
    dst[1] = pack2(r2, r3);
    #pragma unroll
    for (int z=0; z<14; ++z) dst[2+z] = 0u;
  }
  __syncthreads();

  int lane = tid & 63;
  int wv = __builtin_amdgcn_readfirstlane(tid >> 6);

  { f32x4 acc[4][4];
    layer_compute<9>(Abuf, wfrag + FO_L0, cvt + O_MLPB0, lane, wv, acc);
    __syncthreads(); layer_store(Abuf, acc, lane, wv); }
  __syncthreads();
  { f32x4 acc[4][4];
    layer_compute<8>(Abuf, wfrag + FO_L1, cvt + O_MLPB1, lane, wv, acc);
    __syncthreads(); layer_store(Abuf, acc, lane, wv); }
  __syncthreads();
  { f32x4 acc[4][4];
    layer_compute<8>(Abuf, wfrag + FO_L2, cvt + O_MLPB2, lane, wv, acc);
    __syncthreads(); layer_store(Abuf, acc, lane, wv); }
  __syncthreads();
  { f32x4 acc[4][4];
    layer_compute<8>(Abuf, wfrag + FO_L3, cvt + O_MLPB3, lane, wv, acc);
    __syncthreads(); layer_store(Abuf, acc, lane, wv); }
  __syncthreads();

  // ---- layer 4 (256->3): wave wv handles m-tile wv, single N-tile (cols 0..2 valid) ----
  {
    int col = lane & 15, quad = lane >> 4;
    float bv = (col < 3) ? cvt[O_MLPB4 + col] : 0.f;
    f32x4 a4 = (f32x4){bv,bv,bv,bv};
    for (int kc=0; kc<8; ++kc){
      bf16x8 av = *(const bf16x8*)(Abuf + (wv*16 + col)*AST + kc*32 + quad*8);
      bf16x8 bv8 = *(const bf16x8*)(wfrag + FO_L4 + (kc*64 + lane)*8);
      a4 = __builtin_amdgcn_mfma_f32_16x16x32_bf16(av, bv8, a4, 0, 0, 0);
    }
    if (col < 3){
      #pragma unroll
      for (int r=0;r<4;++r)
        predbuf[(wv*16 + quad*4 + r)*3 + col] = a4[r];
    }
  }
  __syncthreads();

  // ---- ensemble combine + bilinear(inp) + store ----
  if (tid < 16){
    int gq = blockIdx.x*16 + tid;
    int b = gq >> 14, q = gq & 16383;
    float cy = cvt[O_COORD + (b*16384+q)*2 + 0];
    float cx = cvt[O_COORD + (b*16384+q)*2 + 1];
    float a[4];
    #pragma unroll
    for (int e=0;e<4;++e){
      float cy_, cx_; shifted_coord(cy, cx, e, cy_, cx_);
      int iy = nidx(cy_, 48), ix = nidx(cx_, 48);
      float qy = -1.f + (2.f*iy + 1.f)*(1.f/48.f);
      float qx = -1.f + (2.f*ix + 1.f)*(1.f/48.f);
      float ry = (cy - qy)*48.f, rx = (cx - qx)*48.f;
      a[e] = fabsf(ry*rx) + 1e-9f;
    }
    float tot = a[0]+a[1]+a[2]+a[3];
    float fy = fminf(fmaxf((cy+1.f)*24.f - 0.5f, 0.f), 47.f);
    float fx = fminf(fmaxf((cx+1.f)*24.f - 0.5f, 0.f), 47.f);
    float y0f = floorf(fy), x0f = floorf(fx);
    float wy = fy - y0f, wx = fx - x0f;
    int y0 = (int)y0f, x0 = (int)x0f;
    int y1 = min(y0+1, 47), x1 = min(x0+1, 47);
    int bf = *flagp;
    #pragma unroll
    for (int ch=0; ch<3; ++ch){
      const float* ip = cvt + O_INP + (b*3 + ch)*2304;
      float v00 = ip[y0*48+x0], v01 = ip[y0*48+x1], v10 = ip[y1*48+x0], v11 = ip[y1*48+x1];
      float v = v00*(1.f-wy)*(1.f-wx) + v01*(1.f-wy)*wx + v10*wy*(1.f-wx) + v11*wy*wx;
      #pragma unroll
      for (int e=0;e<4;++e)
        v += predbuf[(tid*4+e)*3 + ch] * (a[3-e]/tot);   // local-ensemble diagonal swap
      int oi = (b*16384+q)*3 + ch;
      if (bf) ((u16*)outv)[oi] = f2bf(v);
      else    ((float*)outv)[oi] = v;
    }
  }
}

extern "C" void kernel_launch(void* const* d_in, const int* in_sizes, int n_in,
                              void* d_out, int out_size, void* d_ws, size_t ws_size,
                              hipStream_t stream){
  float* ws = (float*)d_ws;
  int* flag = (int*)d_ws;
  float* cvt = ws + W_CVT;
  Ptrs ptrs;
  for (int i = 0; i < NIN && i < n_in; ++i) ptrs.p[i] = d_in[i];

  k_detect<<<1, 64, 0, stream>>>(d_in[2], flag);
  k_convert<<<(CVT_TOTAL+255)/256, 256, 0, stream>>>(ptrs, flag, cvt);
  k_repack<<<2048, 256, 0, stream>>>(cvt, ws);
  k_repack_mlp<<<FRAG_TOTAL/256, 256, 0, stream>>>(cvt, (u16*)(ws + W_MFW));
  k_enc<<<2304, 256, 0, stream>>>(cvt, ws + W_FEAT);
  k_upconv<48> <<<dim3(36, 4), 256, 0, stream>>>(ws+W_FEAT,  ws+W_UP1R, cvt+O_UP1B, ws+W_FEAT1);
  k_upconv<96> <<<dim3(144,4), 256, 0, stream>>>(ws+W_FEAT1, ws+W_UP2R, cvt+O_UP2B, ws+W_FEAT2);
  k_upconv<192><<<dim3(576,4), 256, 0, stream>>>(ws+W_FEAT2, ws+W_UP3R, cvt+O_UP3B, ws+W_FEAT3);
  k_downconv<192><<<dim3(576,4), 256, 0, stream>>>(ws+W_FEAT3, ws+W_D4R, cvt+O_DN4B, ws+W_FEAT4);
  k_skip<192>    <<<dim3(576,4), 256, 0, stream>>>(ws+W_FEAT2, ws+W_S1R, cvt+O_SK1B, ws+W_FEAT4);
  k_downconv<96> <<<dim3(144,4), 256, 0, stream>>>(ws+W_FEAT4, ws+W_D5R, cvt+O_DN5B, ws+W_FEAT5);
  k_skip<96>     <<<dim3(144,4), 256, 0, stream>>>(ws+W_FEAT1, ws+W_S2R, cvt+O_SK2B, ws+W_FEAT5);
  k_query<<<4096, 256, 0, stream>>>(cvt, ws+W_FEAT, ws+W_FEAT3, ws+W_FEAT4, ws+W_FEAT5,
                                    (const u16*)(ws + W_MFW), flag, d_out);
}

// Round 4
// 433.205 us; speedup vs baseline: 10.5225x; 5.1261x over previous
//
#include <hip/hip_runtime.h>
#include <stdint.h>

typedef unsigned int u32;
typedef unsigned short u16;

#define DI __device__ __forceinline__

DI float bf2f(u16 h){ return __uint_as_float(((u32)h)<<16); }
DI u16 f2bf(float f){ u32 u = __float_as_uint(f); return (u16)((u + 0x7FFFu + ((u>>16)&1u))>>16); }
DI u32 pack2(float a, float b){ return (u32)f2bf(a) | ((u32)f2bf(b)<<16); }

typedef __attribute__((ext_vector_type(8))) short bf16x8;
typedef __attribute__((ext_vector_type(4))) float f32x4;

// ---------------- input table (element counts / offsets in fp32 staging buf) ----------------
#define NIN 29
__device__ const int g_in_off[NIN] = {
  0,27648,158720,289792,291520,291584,439040,439296,586752,587008,734464,
  734720,738816,738880,742976,743040,779904,779968,816832,816896,883456,
  883712,949248,949504,1015040,1015296,1080832,1081088,1081856};
#define CVT_TOTAL 1081859

// cvt-buffer float offsets
#define O_INP      0
#define O_COORD    27648
#define O_CELL     158720
#define O_ENCW     289792
#define O_ENCB     291520
#define O_UP1W     291584
#define O_UP1B     439040
#define O_UP2W     439296
#define O_UP2B     586752
#define O_UP3W     587008
#define O_UP3B     734464
#define O_SK1W     734720
#define O_SK1B     738816
#define O_SK2W     738880
#define O_SK2B     742976
#define O_DN4W     743040
#define O_DN4B     779904
#define O_DN5W     779968
#define O_DN5B     816832
#define O_MLPW0    816896
#define O_MLPB0    883456
#define O_MLPW1    883712
#define O_MLPB1    949248
#define O_MLPW2    949504
#define O_MLPB2    1015040
#define O_MLPW3    1015296
#define O_MLPB3    1080832
#define O_MLPW4    1081088
#define O_MLPB4    1081856

// ---------------- workspace layout (float offsets) ----------------
#define W_CVT    16
#define W_FRAG   1082000     // u16 fragment region (conv + mlp), 798720 u16 = 399360 floats
// fragment sub-offsets (u16 elements within W_FRAG)
#define FG_UP1 0
#define FG_UP2 147456
#define FG_UP3 294912
#define FG_D4  442368
#define FG_D5  483328
#define CONV_FRAG_TOTAL 524288
#define FG_MLP 524288
// MLP fragment layer offsets (u16, relative to FG_MLP)
#define FO_L0 0
#define FO_L1 73728
#define FO_L2 139264
#define FO_L3 204800
#define FO_L4 270336
#define FRAG_TOTAL 274432
// feature maps: bf16 NHWC (float offsets; cast to u16*)
// sizes (floats): feat 294912, feat1/feat5 1179648, feat2/feat4 4718592, feat3 18874368
#define W_FEAT   1481360    // 48x48x64 x4  -> ends 1776272
#define W_FEAT1  1776272    // 96          -> ends 2955920
#define W_FEAT2  2955920    // 192         -> ends 7674512
#define W_FEAT3  7674512    // 384         -> ends 26548880
#define W_FEAT4  26548880   // 192         -> ends 31267472
#define W_FEAT5  31267472   // 96          -> ends 32447120
// end: 32447120 floats = 129.8 MB

#define AST 296   // Abuf row stride in bf16

// ---------------- dtype detect: cell is constant 2/384 ----------------
__global__ void k_detect(const void* cell, int* flag){
  if (threadIdx.x == 0 && blockIdx.x == 0){
    u32 u = *(const u32*)cell;
    *flag = ((u >> 16) == (u & 0xFFFFu)) ? 1 : 0;
  }
}

struct Ptrs { const void* p[NIN]; };

__global__ __launch_bounds__(256) void k_convert(Ptrs ptrs, const int* __restrict__ flag, float* __restrict__ dst){
  int idx = blockIdx.x*256 + threadIdx.x;
  if (idx >= CVT_TOTAL) return;
  int bf = *flag;
  int i = 0;
  #pragma unroll
  for (int s = 1; s < NIN; ++s) if (idx >= g_in_off[s]) i = s;
  int local = idx - g_in_off[i];
  float v;
  if (bf) v = bf2f(((const u16*)ptrs.p[i])[local]);
  else    v = ((const float*)ptrs.p[i])[local];
  dst[idx] = v;
}

// ---------------- conv weight repack -> MFMA B-fragment order (bf16) ----------------
// up layers: K=576 (k=(dy*3+dx)*64+ci), N=256 with perm co=(wv*16+col)*4+nt
// down layers (fused skip): K=640 (576 conv + 64 skip), N=64, co=nt*16+col
__global__ __launch_bounds__(256) void k_repack_conv(const float* __restrict__ cvt, u16* __restrict__ dst){
  int idx = blockIdx.x*256 + threadIdx.x;   // covers CONV_FRAG_TOTAL exactly
  float v;
  if (idx < 442368){
    int seg = idx / 147456, base = idx % 147456;
    const int wo[3] = {O_UP1W, O_UP2W, O_UP3W};
    int t = base & 511, c = base >> 9;      // c in [0,288)
    int j = t & 7, lane = t >> 3;
    int col = lane & 15, quad = lane >> 4;
    int kc = c >> 4, rem = c & 15;
    int wv = rem >> 2, nt = rem & 3;
    int k = kc*32 + quad*8 + j;             // < 576
    int kid = k >> 6, ci = k & 63;
    int co = (wv*16 + col)*4 + nt;
    v = cvt[wo[seg] + co*576 + ci*9 + kid];
  } else {
    int x = idx - 442368;
    int seg = x / 40960, base = x % 40960;
    int t = base & 511, c = base >> 9;      // c in [0,80)
    int j = t & 7, lane = t >> 3;
    int col = lane & 15, quad = lane >> 4;
    int kc = c >> 2, nt = c & 3;
    int k = kc*32 + quad*8 + j;
    int co = nt*16 + col;
    if (k < 576){
      int kid = k >> 6, ci = k & 63;
      v = cvt[(seg ? O_DN5W : O_DN4W) + co*576 + ci*9 + kid];
    } else {
      int ci = k - 576;
      v = cvt[(seg ? O_SK2W : O_SK1W) + co*64 + ci];
    }
  }
  dst[idx] = f2bf(v);
}

// ---------------- MLP weight repack into MFMA B-fragment order (bf16) ----------------
__global__ __launch_bounds__(256) void k_repack_mlp(const float* __restrict__ cvt, u16* __restrict__ dst){
  int idx = blockIdx.x*256 + threadIdx.x;   // grid covers FRAG_TOTAL exactly
  int l, base;
  if (idx < FO_L1)      { l = 0; base = idx; }
  else if (idx < FO_L2) { l = 1; base = idx - FO_L1; }
  else if (idx < FO_L3) { l = 2; base = idx - FO_L2; }
  else if (idx < FO_L4) { l = 3; base = idx - FO_L3; }
  else                  { l = 4; base = idx - FO_L4; }
  int t = base & 511, c = base >> 9;
  int L = t >> 3, j = t & 7;
  int ntiles = (l == 4) ? 1 : 16;
  int kc = c / ntiles, nt = c % ntiles;
  int k = kc*32 + (L>>4)*8 + j;
  int n = nt*16 + (L&15);
  const int srcw[5] = {O_MLPW0, O_MLPW1, O_MLPW2, O_MLPW3, O_MLPW4};
  int Kvalid = (l == 0) ? 260 : 256;
  int N = (l == 4) ? 3 : 256;
  float v = 0.f;
  if (k < Kvalid && n < N) v = cvt[srcw[l] + k*N + n];
  dst[idx] = f2bf(v);
}

// ---------------- enc conv: 3->64, 3x3 pad1, NCHW fp32 in, NHWC bf16 out ----------------
__global__ __launch_bounds__(256) void k_enc(const float* __restrict__ cvt, u16* __restrict__ feat){
  int gid = blockIdx.x*256 + threadIdx.x;
  int co = gid & 63, pix = gid >> 6;
  int x = pix % 48; int t = pix / 48; int y = t % 48; int b = t / 48;
  const float* w = cvt + O_ENCW + co*27;
  float acc = cvt[O_ENCB + co];
  const float* ip = cvt + O_INP + b*3*2304;
  #pragma unroll
  for (int ci = 0; ci < 3; ++ci)
    for (int dy = 0; dy < 3; ++dy){
      int iy = y + dy - 1;
      for (int dx = 0; dx < 3; ++dx){
        int ix = x + dx - 1;
        float v = (iy>=0 && iy<48 && ix>=0 && ix<48) ? ip[ci*2304 + iy*48 + ix] : 0.f;
        acc = fmaf(w[ci*9 + dy*3 + dx], v, acc);
      }
    }
  feat[pix*64 + co] = f2bf(acc);
}

// ---------------- MFMA upconv 64->256 3x3 pad1 + fused pixel-shuffle, bf16 NHWC ----------------
template<int H>
__global__ __launch_bounds__(256,2) void k_upconv_mfma(const u16* __restrict__ in,
    const u16* __restrict__ wf, const float* __restrict__ bias, u16* __restrict__ out){
  __shared__ __align__(16) u16 patch[100*72];   // 10x10 px, 64ch + pad8
  const int TW = H/8;
  int b = blockIdx.y;
  int y0 = (blockIdx.x / TW)*8, x0 = (blockIdx.x % TW)*8;
  int tid = threadIdx.x;
  if (tid < 200){
    int p = tid >> 1, half = tid & 1;
    int pr = p/10, pc = p - pr*10;
    int gy = y0+pr-1, gx = x0+pc-1;
    uint4* dst = (uint4*)((char*)(patch + p*72) + half*64);
    if (gy>=0 && gy<H && gx>=0 && gx<H){
      const uint4* src = (const uint4*)((const char*)(in + ((b*H+gy)*H+gx)*64) + half*64);
      dst[0]=src[0]; dst[1]=src[1]; dst[2]=src[2]; dst[3]=src[3];
    } else {
      uint4 z = {0,0,0,0};
      dst[0]=z; dst[1]=z; dst[2]=z; dst[3]=z;
    }
  }
  __syncthreads();
  int lane = tid & 63, wv = __builtin_amdgcn_readfirstlane(tid>>6);
  int col = lane & 15, quad = lane >> 4;
  f32x4 acc[4][4];
  #pragma unroll
  for (int nt=0;nt<4;++nt){
    float bv = bias[(wv*16+col)*4+nt];
    #pragma unroll
    for (int mt=0;mt<4;++mt) acc[mt][nt] = (f32x4){bv,bv,bv,bv};
  }
  int pyc[4], pxc[4];
  #pragma unroll
  for (int mt=0;mt<4;++mt){ int p = mt*16+col; pyc[mt]=p>>3; pxc[mt]=p&7; }
  #pragma unroll
  for (int kc=0; kc<18; ++kc){
    int dydx = kc>>1, half = kc&1;
    int dy = dydx/3, dx = dydx%3;
    bf16x8 a[4], bb[4];
    #pragma unroll
    for (int mt=0;mt<4;++mt)
      a[mt] = *(const bf16x8*)(patch + ((pyc[mt]+dy)*10 + pxc[mt]+dx)*72 + half*32 + quad*8);
    #pragma unroll
    for (int nt=0;nt<4;++nt)
      bb[nt] = *(const bf16x8*)(wf + ((kc*16 + wv*4 + nt)*64 + lane)*8);
    #pragma unroll
    for (int mt=0;mt<4;++mt)
      #pragma unroll
      for (int nt=0;nt<4;++nt)
        acc[mt][nt] = __builtin_amdgcn_mfma_f32_16x16x32_bf16(a[mt], bb[nt], acc[mt][nt], 0,0,0);
  }
  // pixel-shuffle store: co=(wv*16+col)*4+nt -> c2=wv*16+col, subpixel rs=nt
  const int W2 = 2*H;
  #pragma unroll
  for (int mt=0;mt<4;++mt)
    #pragma unroll
    for (int r=0;r<4;++r){
      int p = mt*16 + quad*4 + r;
      int oy = 2*(y0 + (p>>3)), ox = 2*(x0 + (p&7));
      #pragma unroll
      for (int nt=0;nt<4;++nt)
        out[((b*W2 + oy + (nt>>1))*W2 + ox + (nt&1))*64 + wv*16 + col] = f2bf(acc[mt][nt][r]);
    }
}

// ---------------- MFMA stride-2 downconv 64->64 + fused 1x1 skip, bf16 NHWC ----------------
template<int HO>
__global__ __launch_bounds__(256,2) void k_down_mfma(const u16* __restrict__ in3,
    const u16* __restrict__ in2, const u16* __restrict__ wf,
    const float* __restrict__ biasd, const float* __restrict__ biass, u16* __restrict__ out){
  __shared__ __align__(16) u16 patch3[289*72];  // 17x17 px
  __shared__ __align__(16) u16 patch2[64*72];   // 8x8 px (skip input)
  const int HI = 2*HO, TW = HO/8;
  int b = blockIdx.y;
  int y0 = (blockIdx.x / TW)*8, x0 = (blockIdx.x % TW)*8;
  int tid = threadIdx.x;
  for (int u = tid; u < 578; u += 256){
    int p = u >> 1, half = u & 1;
    int pr = p/17, pc = p - pr*17;
    int gy = 2*y0 - 1 + pr, gx = 2*x0 - 1 + pc;
    uint4* dst = (uint4*)((char*)(patch3 + p*72) + half*64);
    if (gy>=0 && gy<HI && gx>=0 && gx<HI){
      const uint4* src = (const uint4*)((const char*)(in3 + ((b*HI+gy)*HI+gx)*64) + half*64);
      dst[0]=src[0]; dst[1]=src[1]; dst[2]=src[2]; dst[3]=src[3];
    } else { uint4 z={0,0,0,0}; dst[0]=z; dst[1]=z; dst[2]=z; dst[3]=z; }
  }
  if (tid < 128){
    int p = tid >> 1, half = tid & 1;
    int gy = y0 + (p>>3), gx = x0 + (p&7);
    uint4* dst = (uint4*)((char*)(patch2 + p*72) + half*64);
    const uint4* src = (const uint4*)((const char*)(in2 + ((b*HO+gy)*HO+gx)*64) + half*64);
    dst[0]=src[0]; dst[1]=src[1]; dst[2]=src[2]; dst[3]=src[3];
  }
  __syncthreads();
  int lane = tid & 63, wv = __builtin_amdgcn_readfirstlane(tid>>6);
  int col = lane & 15, quad = lane >> 4;
  f32x4 acc[4];
  {
    float bv = biasd[wv*16+col] + biass[wv*16+col];
    #pragma unroll
    for (int mt=0;mt<4;++mt) acc[mt] = (f32x4){bv,bv,bv,bv};
  }
  int pyc[4], pxc[4];
  #pragma unroll
  for (int mt=0;mt<4;++mt){ int p = mt*16+col; pyc[mt]=p>>3; pxc[mt]=p&7; }
  #pragma unroll
  for (int kc=0; kc<20; ++kc){
    bf16x8 a[4];
    if (kc < 18){
      int dydx = kc>>1, half = kc&1;
      int dy = dydx/3, dx = dydx%3;
      #pragma unroll
      for (int mt=0;mt<4;++mt)
        a[mt] = *(const bf16x8*)(patch3 + ((2*pyc[mt]+dy)*17 + 2*pxc[mt]+dx)*72 + half*32 + quad*8);
    } else {
      #pragma unroll
      for (int mt=0;mt<4;++mt)
        a[mt] = *(const bf16x8*)(patch2 + (pyc[mt]*8+pxc[mt])*72 + (kc-18)*32 + quad*8);
    }
    bf16x8 bb = *(const bf16x8*)(wf + ((kc*4 + wv)*64 + lane)*8);
    #pragma unroll
    for (int mt=0;mt<4;++mt)
      acc[mt] = __builtin_amdgcn_mfma_f32_16x16x32_bf16(a[mt], bb, acc[mt], 0,0,0);
  }
  #pragma unroll
  for (int mt=0;mt<4;++mt)
    #pragma unroll
    for (int r=0;r<4;++r){
      int p = mt*16 + quad*4 + r;
      out[((b*HO + y0+(p>>3))*HO + x0+(p&7))*64 + wv*16+col] = f2bf(acc[mt][r]);
    }
}

// ---------------- query stage helpers (fp32 op sequence matched to numpy) ----------------
DI void shifted_coord(float cy, float cx, int e, float& cy_, float& cx_){
  float vx = (e & 2) ? 1.f : -1.f;
  float vy = (e & 1) ? 1.f : -1.f;
  float sy = (float)((double)vx*(1.0/48.0) + 1e-6);
  float sx = (float)((double)vy*(1.0/48.0) + 1e-6);
  const float clo = (float)(-1.0 + 1e-6), chi = (float)(1.0 - 1e-6);
  cy_ = fminf(fmaxf(__fadd_rn(cy, sy), clo), chi);
  cx_ = fminf(fmaxf(__fadd_rn(cx, sx), clo), chi);
}
DI int nidx(float c_, int hL){
  float f = __fadd_rn(__fmul_rn(__fadd_rn(c_, 1.f), (float)hL*0.5f), -0.5f);
  int i = (int)rintf(f);
  return max(0, min(hL-1, i));
}

// ---------------- MFMA MLP layer helpers ----------------
template<int KC>
DI void layer_compute(const u16* __restrict__ Ab, const u16* __restrict__ wf,
                      const float* __restrict__ bias, int lane, int wv, f32x4 (&acc)[4][4]){
  int col = lane & 15, quad = lane >> 4;
  #pragma unroll
  for (int mt=0;mt<4;++mt)
    #pragma unroll
    for (int nt=0;nt<4;++nt){
      float bv = bias[wv*64 + nt*16 + col];
      acc[mt][nt] = (f32x4){bv,bv,bv,bv};
    }
  for (int kc=0; kc<KC; ++kc){
    bf16x8 a[4], b[4];
    #pragma unroll
    for (int mt=0;mt<4;++mt)
      a[mt] = *(const bf16x8*)(Ab + (mt*16+col)*AST + kc*32 + quad*8);
    #pragma unroll
    for (int nt=0;nt<4;++nt)
      b[nt] = *(const bf16x8*)(wf + ((kc*16 + wv*4 + nt)*64 + lane)*8);
    #pragma unroll
    for (int mt=0;mt<4;++mt)
      #pragma unroll
      for (int nt=0;nt<4;++nt)
        acc[mt][nt] = __builtin_amdgcn_mfma_f32_16x16x32_bf16(a[mt], b[nt], acc[mt][nt], 0, 0, 0);
  }
}

DI void layer_store(u16* __restrict__ Ab, f32x4 (&acc)[4][4], int lane, int wv){
  int col = lane & 15, quad = lane >> 4;
  #pragma unroll
  for (int mt=0;mt<4;++mt)
    #pragma unroll
    for (int nt=0;nt<4;++nt)
      #pragma unroll
      for (int r=0;r<4;++r)
        Ab[(mt*16 + quad*4 + r)*AST + wv*64 + nt*16 + col] = f2bf(fmaxf(acc[mt][nt][r], 0.f));
}

// ---------------- fused gather + MFMA MLP + ensemble + bilinear ----------------
__global__ __launch_bounds__(256) void k_query(const float* __restrict__ cvt,
    const u16* __restrict__ feat, const u16* __restrict__ feat3,
    const u16* __restrict__ feat4, const u16* __restrict__ feat5,
    const u16* __restrict__ wfrag, const int* __restrict__ flagp, void* __restrict__ outv){
  __shared__ __align__(16) u16 Abuf[64*AST];      // 37888 B, [row m][k]
  __shared__ float predbuf[64*3];
  int tid = threadIdx.x;

  // ---- gather: 64 rows (16 queries x 4 ensembles), 4 parts/row = 4 pyramid levels ----
  {
    int r = tid >> 2, part = tid & 3;
    int gq = blockIdx.x*16 + (r>>2);
    int e = r & 3;
    int b = gq >> 14, q = gq & 16383;
    float cy = cvt[O_COORD + (b*16384+q)*2 + 0];
    float cx = cvt[O_COORD + (b*16384+q)*2 + 1];
    float cy_, cx_; shifted_coord(cy, cx, e, cy_, cx_);
    int hL = (part==0) ? 48 : (part==1) ? 96 : (part==2) ? 192 : 384;
    const u16* fp = (part==0) ? feat : (part==1) ? feat5 : (part==2) ? feat4 : feat3;
    int iy = nidx(cy_, hL), ix = nidx(cx_, hL);
    const uint4* src = (const uint4*)(fp + ((b*hL + iy)*hL + ix)*64);
    uint4* dst = (uint4*)((char*)Abuf + r*(AST*2) + part*128);
    #pragma unroll
    for (int i=0;i<8;++i) dst[i] = src[i];
  }
  // ---- rel features into K=256..259, zeros to 287 ----
  if (tid < 64){
    int gq = blockIdx.x*16 + (tid>>2);
    int e = tid & 3;
    int b = gq >> 14, q = gq & 16383;
    float cy = cvt[O_COORD + (b*16384+q)*2 + 0];
    float cx = cvt[O_COORD + (b*16384+q)*2 + 1];
    float cy_, cx_; shifted_coord(cy, cx, e, cy_, cx_);
    int iy = nidx(cy_, 48), ix = nidx(cx_, 48);
    float qy = -1.f + (2.f*iy + 1.f)*(1.f/48.f);
    float qx = -1.f + (2.f*ix + 1.f)*(1.f/48.f);
    float r0 = (cy - qy)*48.f;
    float r1 = (cx - qx)*48.f;
    float r2 = cvt[O_CELL + (b*16384+q)*2 + 0]*48.f;
    float r3 = cvt[O_CELL + (b*16384+q)*2 + 1]*48.f;
    u32* dst = (u32*)((char*)Abuf + tid*(AST*2) + 512);
    dst[0] = pack2(r0, r1);
    dst[1] = pack2(r2, r3);
    #pragma unroll
    for (int z=0; z<14; ++z) dst[2+z] = 0u;
  }
  __syncthreads();

  int lane = tid & 63;
  int wv = __builtin_amdgcn_readfirstlane(tid >> 6);

  { f32x4 acc[4][4];
    layer_compute<9>(Abuf, wfrag + FO_L0, cvt + O_MLPB0, lane, wv, acc);
    __syncthreads(); layer_store(Abuf, acc, lane, wv); }
  __syncthreads();
  { f32x4 acc[4][4];
    layer_compute<8>(Abuf, wfrag + FO_L1, cvt + O_MLPB1, lane, wv, acc);
    __syncthreads(); layer_store(Abuf, acc, lane, wv); }
  __syncthreads();
  { f32x4 acc[4][4];
    layer_compute<8>(Abuf, wfrag + FO_L2, cvt + O_MLPB2, lane, wv, acc);
    __syncthreads(); layer_store(Abuf, acc, lane, wv); }
  __syncthreads();
  { f32x4 acc[4][4];
    layer_compute<8>(Abuf, wfrag + FO_L3, cvt + O_MLPB3, lane, wv, acc);
    __syncthreads(); layer_store(Abuf, acc, lane, wv); }
  __syncthreads();

  // ---- layer 4 (256->3): wave wv handles m-tile wv ----
  {
    int col = lane & 15, quad = lane >> 4;
    float bv = (col < 3) ? cvt[O_MLPB4 + col] : 0.f;
    f32x4 a4 = (f32x4){bv,bv,bv,bv};
    for (int kc=0; kc<8; ++kc){
      bf16x8 av = *(const bf16x8*)(Abuf + (wv*16 + col)*AST + kc*32 + quad*8);
      bf16x8 bv8 = *(const bf16x8*)(wfrag + FO_L4 + (kc*64 + lane)*8);
      a4 = __builtin_amdgcn_mfma_f32_16x16x32_bf16(av, bv8, a4, 0, 0, 0);
    }
    if (col < 3){
      #pragma unroll
      for (int r=0;r<4;++r)
        predbuf[(wv*16 + quad*4 + r)*3 + col] = a4[r];
    }
  }
  __syncthreads();

  // ---- ensemble combine + bilinear(inp) + store ----
  if (tid < 16){
    int gq = blockIdx.x*16 + tid;
    int b = gq >> 14, q = gq & 16383;
    float cy = cvt[O_COORD + (b*16384+q)*2 + 0];
    float cx = cvt[O_COORD + (b*16384+q)*2 + 1];
    float a[4];
    #pragma unroll
    for (int e=0;e<4;++e){
      float cy_, cx_; shifted_coord(cy, cx, e, cy_, cx_);
      int iy = nidx(cy_, 48), ix = nidx(cx_, 48);
      float qy = -1.f + (2.f*iy + 1.f)*(1.f/48.f);
      float qx = -1.f + (2.f*ix + 1.f)*(1.f/48.f);
      float ry = (cy - qy)*48.f, rx = (cx - qx)*48.f;
      a[e] = fabsf(ry*rx) + 1e-9f;
    }
    float tot = a[0]+a[1]+a[2]+a[3];
    float fy = fminf(fmaxf((cy+1.f)*24.f - 0.5f, 0.f), 47.f);
    float fx = fminf(fmaxf((cx+1.f)*24.f - 0.5f, 0.f), 47.f);
    float y0f = floorf(fy), x0f = floorf(fx);
    float wy = fy - y0f, wx = fx - x0f;
    int y0 = (int)y0f, x0 = (int)x0f;
    int y1 = min(y0+1, 47), x1 = min(x0+1, 47);
    int bf = *flagp;
    #pragma unroll
    for (int ch=0; ch<3; ++ch){
      const float* ip = cvt + O_INP + (b*3 + ch)*2304;
      float v00 = ip[y0*48+x0], v01 = ip[y0*48+x1], v10 = ip[y1*48+x0], v11 = ip[y1*48+x1];
      float v = v00*(1.f-wy)*(1.f-wx) + v01*(1.f-wy)*wx + v10*wy*(1.f-wx) + v11*wy*wx;
      #pragma unroll
      for (int e=0;e<4;++e)
        v += predbuf[(tid*4+e)*3 + ch] * (a[3-e]/tot);   // local-ensemble diagonal swap
      int oi = (b*16384+q)*3 + ch;
      if (bf) ((u16*)outv)[oi] = f2bf(v);
      else    ((float*)outv)[oi] = v;
    }
  }
}

extern "C" void kernel_launch(void* const* d_in, const int* in_sizes, int n_in,
                              void* d_out, int out_size, void* d_ws, size_t ws_size,
                              hipStream_t stream){
  float* ws = (float*)d_ws;
  int* flag = (int*)d_ws;
  float* cvt = ws + W_CVT;
  u16* frag = (u16*)(ws + W_FRAG);
  u16* feat  = (u16*)(ws + W_FEAT);
  u16* feat1 = (u16*)(ws + W_FEAT1);
  u16* feat2 = (u16*)(ws + W_FEAT2);
  u16* feat3 = (u16*)(ws + W_FEAT3);
  u16* feat4 = (u16*)(ws + W_FEAT4);
  u16* feat5 = (u16*)(ws + W_FEAT5);
  Ptrs ptrs;
  for (int i = 0; i < NIN && i < n_in; ++i) ptrs.p[i] = d_in[i];

  k_detect<<<1, 64, 0, stream>>>(d_in[2], flag);
  k_convert<<<(CVT_TOTAL+255)/256, 256, 0, stream>>>(ptrs, flag, cvt);
  k_repack_conv<<<CONV_FRAG_TOTAL/256, 256, 0, stream>>>(cvt, frag);
  k_repack_mlp<<<FRAG_TOTAL/256, 256, 0, stream>>>(cvt, frag + FG_MLP);
  k_enc<<<2304, 256, 0, stream>>>(cvt, feat);
  k_upconv_mfma<48> <<<dim3(36, 4), 256, 0, stream>>>(feat,  frag+FG_UP1, cvt+O_UP1B, feat1);
  k_upconv_mfma<96> <<<dim3(144,4), 256, 0, stream>>>(feat1, frag+FG_UP2, cvt+O_UP2B, feat2);
  k_upconv_mfma<192><<<dim3(576,4), 256, 0, stream>>>(feat2, frag+FG_UP3, cvt+O_UP3B, feat3);
  k_down_mfma<192><<<dim3(576,4), 256, 0, stream>>>(feat3, feat2, frag+FG_D4, cvt+O_DN4B, cvt+O_SK1B, feat4);
  k_down_mfma<96> <<<dim3(144,4), 256, 0, stream>>>(feat4, feat1, frag+FG_D5, cvt+O_DN5B, cvt+O_SK2B, feat5);
  k_query<<<4096, 256, 0, stream>>>(cvt, feat, feat3, feat4, feat5, frag + FG_MLP, flag, d_out);
}